// Round 2
// baseline (739.543 us; speedup 1.0000x reference)
//
#include <hip/hip_runtime.h>

#define N_NODES 50000
#define N_EDGES 1600000
#define D_IN    128
#define D_EDGE  64
#define D_NODE  128

// ---------------------------------------------------------------------------
// Kernel 1: projR = relu(node_features @ W_fs + b_fs)   [N_NODES, 64]
// One thread per output element. Wave covers f=0..63 of one node row:
//  - x[n][k] is a broadcast load (same addr across wave) -> one transaction
//  - Ws[k*64+f] from LDS: bank = f%32 -> 2-way aliasing (free on CDNA4)
// ---------------------------------------------------------------------------
__global__ __launch_bounds__(256)
void proj_relu_kernel(const float* __restrict__ x,
                      const float* __restrict__ W,   // [128,64]
                      const float* __restrict__ b,   // [64]
                      float* __restrict__ out) {     // [N,64]
    __shared__ float Ws[D_IN * D_EDGE];   // 32 KiB
    for (int i = threadIdx.x; i < D_IN * D_EDGE; i += blockDim.x)
        Ws[i] = W[i];
    __syncthreads();

    int idx = blockIdx.x * blockDim.x + threadIdx.x;
    const int total = N_NODES * D_EDGE;
    if (idx >= total) return;
    int n = idx >> 6;       // / 64
    int f = idx & 63;
    const float* xr = x + n * D_IN;
    float acc = b[f];
#pragma unroll 8
    for (int k = 0; k < D_IN; ++k)
        acc = fmaf(xr[k], Ws[k * D_EDGE + f], acc);
    out[idx] = fmaxf(acc, 0.0f);
}

// ---------------------------------------------------------------------------
// Kernel 2: scatter-max.  One wave per edge, lane = feature.
//  - projR row + agg row reads: coalesced 256B transactions.
//  - READ-BEFORE-ATOMIC: agg values grow monotonically from 0, so if the
//    observed agg[r][f] >= v the final value is guaranteed >= v -> skip.
//    (Stale observations are values that WERE written, so skips stay safe;
//    a stale-small value only costs a redundant atomicMax.)
//  - atomicMax on uint bit patterns is exact for non-negative floats
//    (post-relu); zero-init == reference's empty-segment->0 semantics.
// Expected atomics: ~H(32)*3.2M slots ~= 13M vs 102M naive.
// ---------------------------------------------------------------------------
__global__ __launch_bounds__(256)
void scatter_max_kernel(const float* __restrict__ projR,
                        const int*   __restrict__ senders,
                        const int*   __restrict__ receivers,
                        unsigned int* __restrict__ agg_bits) {
    int tid  = blockIdx.x * blockDim.x + threadIdx.x;
    int e    = tid >> 6;           // wave id = edge id
    int lane = tid & 63;
    if (e >= N_EDGES) return;
    int s = senders[e];            // wave-uniform broadcast load
    int r = receivers[e];
    unsigned int vb = __float_as_uint(projR[s * D_EDGE + lane]);
    unsigned int* slot = agg_bits + r * D_EDGE + lane;
    if (vb > *slot)                // non-negative floats order as uints
        atomicMax(slot, vb);
}

// ---------------------------------------------------------------------------
// Kernel 3: out = x @ W_gn + b_gn + agg @ W_gin + b_gin    [N_NODES, 128]
// One thread per output element; W matrices (96 KiB) L2-resident; x row
// loads are wave-uniform broadcasts; W loads coalesced.
// ---------------------------------------------------------------------------
__global__ __launch_bounds__(256)
void node_out_kernel(const float* __restrict__ x,     // [N,128]
                     const float* __restrict__ W_gn,  // [128,128]
                     const float* __restrict__ b_gn,  // [128]
                     const float* __restrict__ agg,   // [N,64]
                     const float* __restrict__ W_gin, // [64,128]
                     const float* __restrict__ b_gin, // [128]
                     float* __restrict__ out) {       // [N,128]
    int idx = blockIdx.x * blockDim.x + threadIdx.x;
    const int total = N_NODES * D_NODE;
    if (idx >= total) return;
    int n = idx >> 7;       // / 128
    int f = idx & 127;
    const float* xr = x + n * D_IN;
    const float* ar = agg + n * D_EDGE;
    float acc = b_gn[f] + b_gin[f];
#pragma unroll 8
    for (int k = 0; k < D_IN; ++k)
        acc = fmaf(xr[k], W_gn[k * D_NODE + f], acc);
#pragma unroll 8
    for (int k = 0; k < D_EDGE; ++k)
        acc = fmaf(ar[k], W_gin[k * D_NODE + f], acc);
    out[idx] = acc;
}

// ---------------------------------------------------------------------------
extern "C" void kernel_launch(void* const* d_in, const int* in_sizes, int n_in,
                              void* d_out, int out_size, void* d_ws, size_t ws_size,
                              hipStream_t stream) {
    const float* node_features = (const float*)d_in[0];
    const float* W_fs          = (const float*)d_in[1];
    const float* b_fs          = (const float*)d_in[2];
    const float* W_gn          = (const float*)d_in[3];
    const float* b_gn          = (const float*)d_in[4];
    const float* W_gin         = (const float*)d_in[5];
    const float* b_gin         = (const float*)d_in[6];
    const int*   senders       = (const int*)d_in[7];
    const int*   receivers     = (const int*)d_in[8];
    float* out = (float*)d_out;

    // workspace layout: projR [N*64 f32] | agg [N*64 f32]
    float* projR = (float*)d_ws;
    float* agg   = projR + (size_t)N_NODES * D_EDGE;

    // agg must be zero-init every call (harness re-poisons ws with 0xAA)
    hipMemsetAsync(agg, 0, (size_t)N_NODES * D_EDGE * sizeof(float), stream);

    {   // proj+relu: 50000*64 threads
        int total = N_NODES * D_EDGE;
        int blk = 256;
        int grid = (total + blk - 1) / blk;
        proj_relu_kernel<<<grid, blk, 0, stream>>>(node_features, W_fs, b_fs, projR);
    }
    {   // scatter: one wave per edge -> 1.6M waves
        long long total = (long long)N_EDGES * 64;
        int blk = 256;
        long long grid = (total + blk - 1) / blk;
        scatter_max_kernel<<<(int)grid, blk, 0, stream>>>(projR, senders, receivers,
                                                          (unsigned int*)agg);
    }
    {   // final: 50000*128 threads
        int total = N_NODES * D_NODE;
        int blk = 256;
        int grid = (total + blk - 1) / blk;
        node_out_kernel<<<grid, blk, 0, stream>>>(node_features, W_gn, b_gn,
                                                  agg, W_gin, b_gin, out);
    }
}

// Round 3
// 367.379 us; speedup vs baseline: 2.0130x; 2.0130x over previous
//
#include <hip/hip_runtime.h>

#define N_NODES 50000
#define N_EDGES 1600000
#define D_IN    128
#define D_EDGE  64
#define D_NODE  128
#define NB      32      // nodes per block in GEMM kernels

__device__ __forceinline__ float4 fma4(float s, float4 w, float4 a) {
    a.x = fmaf(s, w.x, a.x); a.y = fmaf(s, w.y, a.y);
    a.z = fmaf(s, w.z, a.z); a.w = fmaf(s, w.w, a.w);
    return a;
}

// ---------------------------------------------------------------------------
// Kernel 1: projR = relu(x @ W_fs + b_fs)   [N_NODES, 64]
// Register-tiled: block=256 handles NB=32 nodes. Thread = (fq = tid&15 ->
// 4 feats, slot = tid>>4 -> nodes slot, slot+16). x tile staged in LDS
// (rows padded +4 floats so the 4 slot-rows per wave land in distinct banks).
// Per k0 (4 k): 4 coalesced float4 W loads + 2 ds_read_b128 + 32 FMA.
// ---------------------------------------------------------------------------
__global__ __launch_bounds__(256)
void proj_relu_kernel(const float* __restrict__ x,
                      const float* __restrict__ W,   // [128][64]
                      const float* __restrict__ b,   // [64]
                      float* __restrict__ out) {     // [N][64]
    __shared__ float xs[NB][D_IN + 4];               // ~16.9 KB
    const int tid = threadIdx.x;
    const int nb0 = blockIdx.x * NB;

    // stage x tile (32 float4 per row), zero-fill past N_NODES
    const float4* xv = (const float4*)x;
    for (int i = tid; i < NB * 32; i += 256) {
        int nl = i >> 5, c = i & 31;
        int n = nb0 + nl;
        float4 v = make_float4(0.f, 0.f, 0.f, 0.f);
        if (n < N_NODES) v = xv[(size_t)n * 32 + c];
        *(float4*)&xs[nl][c * 4] = v;
    }
    __syncthreads();

    const int fq = tid & 15;       // f0 = 4*fq
    const int slot = tid >> 4;     // 16 slots
    const float4* W4 = (const float4*)W;   // row k: 16 float4
    float4 bb = ((const float4*)b)[fq];
    float4 acc0 = bb, acc1 = bb;

#pragma unroll 8
    for (int k0 = 0; k0 < D_IN; k0 += 4) {
        float4 w0 = W4[(k0 + 0) * 16 + fq];
        float4 w1 = W4[(k0 + 1) * 16 + fq];
        float4 w2 = W4[(k0 + 2) * 16 + fq];
        float4 w3 = W4[(k0 + 3) * 16 + fq];
        float4 xa = *(const float4*)&xs[slot][k0];
        float4 xb = *(const float4*)&xs[slot + 16][k0];
        acc0 = fma4(xa.x, w0, acc0); acc0 = fma4(xa.y, w1, acc0);
        acc0 = fma4(xa.z, w2, acc0); acc0 = fma4(xa.w, w3, acc0);
        acc1 = fma4(xb.x, w0, acc1); acc1 = fma4(xb.y, w1, acc1);
        acc1 = fma4(xb.z, w2, acc1); acc1 = fma4(xb.w, w3, acc1);
    }

    float4* out4 = (float4*)out;
    int na = nb0 + slot, nbn = nb0 + slot + 16;
    if (na < N_NODES) {
        float4 r = make_float4(fmaxf(acc0.x, 0.f), fmaxf(acc0.y, 0.f),
                               fmaxf(acc0.z, 0.f), fmaxf(acc0.w, 0.f));
        out4[(size_t)na * 16 + fq] = r;
    }
    if (nbn < N_NODES) {
        float4 r = make_float4(fmaxf(acc1.x, 0.f), fmaxf(acc1.y, 0.f),
                               fmaxf(acc1.z, 0.f), fmaxf(acc1.w, 0.f));
        out4[(size_t)nbn * 16 + fq] = r;
    }
}

// ---------------------------------------------------------------------------
// Kernel 2: scatter-max, 8 edges per wave for memory-level parallelism.
// Index loads vectorized (int4); 8 independent row gathers + 8 independent
// agg reads in flight; read-before-atomic filter (values grow monotonically
// from 0; post-relu non-negative floats order as uints).
// ---------------------------------------------------------------------------
#define EPW 8
__global__ __launch_bounds__(256)
void scatter_max_kernel(const float* __restrict__ projR,
                        const int*   __restrict__ senders,
                        const int*   __restrict__ receivers,
                        unsigned int* __restrict__ agg_bits) {
    int tid  = blockIdx.x * blockDim.x + threadIdx.x;
    int wave = tid >> 6;
    int lane = tid & 63;
    int e0 = wave * EPW;
    if (e0 >= N_EDGES) return;

    int4 sa = *(const int4*)(senders + e0);
    int4 sb = *(const int4*)(senders + e0 + 4);
    int4 ra = *(const int4*)(receivers + e0);
    int4 rb = *(const int4*)(receivers + e0 + 4);
    int s[EPW] = {sa.x, sa.y, sa.z, sa.w, sb.x, sb.y, sb.z, sb.w};
    int r[EPW] = {ra.x, ra.y, ra.z, ra.w, rb.x, rb.y, rb.z, rb.w};

    unsigned int v[EPW];
#pragma unroll
    for (int i = 0; i < EPW; ++i)
        v[i] = __float_as_uint(projR[(size_t)s[i] * D_EDGE + lane]);

    unsigned int a[EPW];
#pragma unroll
    for (int i = 0; i < EPW; ++i)
        a[i] = agg_bits[(size_t)r[i] * D_EDGE + lane];

#pragma unroll
    for (int i = 0; i < EPW; ++i) {
        if (v[i] > a[i])
            atomicMax(agg_bits + (size_t)r[i] * D_EDGE + lane, v[i]);
    }
}

// ---------------------------------------------------------------------------
// Kernel 3: out = x @ W_gn + agg @ W_gin + (b_gn + b_gin)   [N_NODES, 128]
// Same register tiling: thread = (fq = tid&31 -> 4 feats, slot = tid>>5 ->
// 4 nodes: slot+{0,8,16,24}). x and agg tiles in LDS (padded).
// Per k0: 4 float4 W loads + 4 ds_read_b128 + 64 FMA.
// ---------------------------------------------------------------------------
__global__ __launch_bounds__(256)
void node_out_kernel(const float* __restrict__ x,     // [N][128]
                     const float* __restrict__ W_gn,  // [128][128]
                     const float* __restrict__ b_gn,  // [128]
                     const float* __restrict__ agg,   // [N][64]
                     const float* __restrict__ W_gin, // [64][128]
                     const float* __restrict__ b_gin, // [128]
                     float* __restrict__ out) {       // [N][128]
    __shared__ float xs[NB][D_IN + 4];                // ~16.9 KB
    __shared__ float as_[NB][D_EDGE + 4];             // ~8.7 KB
    const int tid = threadIdx.x;
    const int nb0 = blockIdx.x * NB;

    const float4* xv = (const float4*)x;
    for (int i = tid; i < NB * 32; i += 256) {
        int nl = i >> 5, c = i & 31;
        int n = nb0 + nl;
        float4 v = make_float4(0.f, 0.f, 0.f, 0.f);
        if (n < N_NODES) v = xv[(size_t)n * 32 + c];
        *(float4*)&xs[nl][c * 4] = v;
    }
    const float4* av = (const float4*)agg;
    for (int i = tid; i < NB * 16; i += 256) {
        int nl = i >> 4, c = i & 15;
        int n = nb0 + nl;
        float4 v = make_float4(0.f, 0.f, 0.f, 0.f);
        if (n < N_NODES) v = av[(size_t)n * 16 + c];
        *(float4*)&as_[nl][c * 4] = v;
    }
    __syncthreads();

    const int fq = tid & 31;       // f0 = 4*fq
    const int slot = tid >> 5;     // 8 slots
    const float4* Wg4 = (const float4*)W_gn;    // row k: 32 float4
    const float4* Wi4 = (const float4*)W_gin;   // row k: 32 float4
    float4 bb = ((const float4*)b_gn)[fq];
    float4 bi = ((const float4*)b_gin)[fq];
    bb.x += bi.x; bb.y += bi.y; bb.z += bi.z; bb.w += bi.w;
    float4 acc0 = bb, acc1 = bb, acc2 = bb, acc3 = bb;

#pragma unroll 4
    for (int k0 = 0; k0 < D_IN; k0 += 4) {
        float4 w0 = Wg4[(k0 + 0) * 32 + fq];
        float4 w1 = Wg4[(k0 + 1) * 32 + fq];
        float4 w2 = Wg4[(k0 + 2) * 32 + fq];
        float4 w3 = Wg4[(k0 + 3) * 32 + fq];
        float4 x0 = *(const float4*)&xs[slot][k0];
        float4 x1 = *(const float4*)&xs[slot + 8][k0];
        float4 x2 = *(const float4*)&xs[slot + 16][k0];
        float4 x3 = *(const float4*)&xs[slot + 24][k0];
        acc0 = fma4(x0.x, w0, acc0); acc0 = fma4(x0.y, w1, acc0);
        acc0 = fma4(x0.z, w2, acc0); acc0 = fma4(x0.w, w3, acc0);
        acc1 = fma4(x1.x, w0, acc1); acc1 = fma4(x1.y, w1, acc1);
        acc1 = fma4(x1.z, w2, acc1); acc1 = fma4(x1.w, w3, acc1);
        acc2 = fma4(x2.x, w0, acc2); acc2 = fma4(x2.y, w1, acc2);
        acc2 = fma4(x2.z, w2, acc2); acc2 = fma4(x2.w, w3, acc2);
        acc3 = fma4(x3.x, w0, acc3); acc3 = fma4(x3.y, w1, acc3);
        acc3 = fma4(x3.z, w2, acc3); acc3 = fma4(x3.w, w3, acc3);
    }

#pragma unroll 4
    for (int k0 = 0; k0 < D_EDGE; k0 += 4) {
        float4 w0 = Wi4[(k0 + 0) * 32 + fq];
        float4 w1 = Wi4[(k0 + 1) * 32 + fq];
        float4 w2 = Wi4[(k0 + 2) * 32 + fq];
        float4 w3 = Wi4[(k0 + 3) * 32 + fq];
        float4 x0 = *(const float4*)&as_[slot][k0];
        float4 x1 = *(const float4*)&as_[slot + 8][k0];
        float4 x2 = *(const float4*)&as_[slot + 16][k0];
        float4 x3 = *(const float4*)&as_[slot + 24][k0];
        acc0 = fma4(x0.x, w0, acc0); acc0 = fma4(x0.y, w1, acc0);
        acc0 = fma4(x0.z, w2, acc0); acc0 = fma4(x0.w, w3, acc0);
        acc1 = fma4(x1.x, w0, acc1); acc1 = fma4(x1.y, w1, acc1);
        acc1 = fma4(x1.z, w2, acc1); acc1 = fma4(x1.w, w3, acc1);
        acc2 = fma4(x2.x, w0, acc2); acc2 = fma4(x2.y, w1, acc2);
        acc2 = fma4(x2.z, w2, acc2); acc2 = fma4(x2.w, w3, acc2);
        acc3 = fma4(x3.x, w0, acc3); acc3 = fma4(x3.y, w1, acc3);
        acc3 = fma4(x3.z, w2, acc3); acc3 = fma4(x3.w, w3, acc3);
    }

    float4* out4 = (float4*)out;
    int n0 = nb0 + slot;
    if (n0 < N_NODES)          out4[(size_t)n0 * 32 + fq]        = acc0;
    if (n0 + 8 < N_NODES)      out4[(size_t)(n0 + 8) * 32 + fq]  = acc1;
    if (n0 + 16 < N_NODES)     out4[(size_t)(n0 + 16) * 32 + fq] = acc2;
    if (n0 + 24 < N_NODES)     out4[(size_t)(n0 + 24) * 32 + fq] = acc3;
}

// ---------------------------------------------------------------------------
extern "C" void kernel_launch(void* const* d_in, const int* in_sizes, int n_in,
                              void* d_out, int out_size, void* d_ws, size_t ws_size,
                              hipStream_t stream) {
    const float* node_features = (const float*)d_in[0];
    const float* W_fs          = (const float*)d_in[1];
    const float* b_fs          = (const float*)d_in[2];
    const float* W_gn          = (const float*)d_in[3];
    const float* b_gn          = (const float*)d_in[4];
    const float* W_gin         = (const float*)d_in[5];
    const float* b_gin         = (const float*)d_in[6];
    const int*   senders       = (const int*)d_in[7];
    const int*   receivers     = (const int*)d_in[8];
    float* out = (float*)d_out;

    // workspace: projR [N*64 f32] | agg [N*64 f32]
    float* projR = (float*)d_ws;
    float* agg   = projR + (size_t)N_NODES * D_EDGE;

    hipMemsetAsync(agg, 0, (size_t)N_NODES * D_EDGE * sizeof(float), stream);

    {   // proj+relu: 32 nodes per block
        int grid = (N_NODES + NB - 1) / NB;
        proj_relu_kernel<<<grid, 256, 0, stream>>>(node_features, W_fs, b_fs, projR);
    }
    {   // scatter: 8 edges per wave, 4 waves per block
        int waves = N_EDGES / EPW;            // 200000
        int grid = (waves + 3) / 4;           // 50000 blocks of 256
        scatter_max_kernel<<<grid, 256, 0, stream>>>(projR, senders, receivers,
                                                     (unsigned int*)agg);
    }
    {   // final GEMM: 32 nodes per block
        int grid = (N_NODES + NB - 1) / NB;
        node_out_kernel<<<grid, 256, 0, stream>>>(node_features, W_gn, b_gn,
                                                  agg, W_gin, b_gin, out);
    }
}